// Round 5
// baseline (110.068 us; speedup 1.0000x reference)
//
#include <hip/hip_runtime.h>

// ---------- helpers ----------
typedef __bf16 bf16x8 __attribute__((ext_vector_type(8)));
typedef float  f32x4  __attribute__((ext_vector_type(4)));
typedef unsigned short u16x8 __attribute__((ext_vector_type(8)));
typedef unsigned int u32;
typedef unsigned long long u64;

static __device__ __forceinline__ unsigned short f32_to_bf16(float f){
  unsigned u = __float_as_uint(f);
  u += 0x7fffu + ((u >> 16) & 1u);          // round-to-nearest-even
  return (unsigned short)(u >> 16);
}
static __device__ __forceinline__ float bf16_to_f32(unsigned short h){
  return __uint_as_float(((unsigned)h) << 16);
}

#define GLOAD_LDS16(g, l)                                                        \
  __builtin_amdgcn_global_load_lds((const __attribute__((address_space(1))) void*)(g), \
                                   (__attribute__((address_space(3))) void*)(l), 16, 0, 0)

// ---------- K0: weight conversion + BN folding ----------
__global__ __launch_bounds__(256) void prep_kernel(
    const float* __restrict__ w1, const float* __restrict__ w2,
    const float* __restrict__ b1, const float* __restrict__ g1, const float* __restrict__ be1,
    const float* __restrict__ m1, const float* __restrict__ v1,
    const float* __restrict__ b2, const float* __restrict__ g2, const float* __restrict__ be2,
    const float* __restrict__ m2, const float* __restrict__ v2,
    unsigned short* __restrict__ w1b, unsigned short* __restrict__ w2b,
    float* __restrict__ sc1, float* __restrict__ sh1,
    float* __restrict__ sc2, float* __restrict__ sh2)
{
  int i = blockIdx.x * 256 + threadIdx.x;
  int stride = gridDim.x * 256;
  for (int k = i; k < 512 * 2048; k += stride) w1b[k] = f32_to_bf16(w1[k]);
  for (int k = i; k < 256 * 512;  k += stride) w2b[k] = f32_to_bf16(w2[k]);
  if (i < 512){
    float s = g1[i] * rsqrtf(v1[i] + 1e-5f);
    sc1[i] = s;
    sh1[i] = (b1[i] - m1[i]) * s + be1[i];   // conv bias folded into BN shift
  } else if (i - 512 < 256){
    int o = i - 512;
    float s = g2[o] * rsqrtf(v2[o] + 1e-5f);
    sc2[o] = s;
    sh2[o] = (b2[o] - m2[o]) * s + be2[o];
  }
}

// ---------- K1: conv1 over full map: Zt[b*4096+p][512] = (W1 . F)^T, bf16 ----------
// grid 512 = 4 b * 64 p-blocks * 2 o-halves; block 256 thr = 4 waves.
// A (weights, 2MB, L2-resident) is read DIRECTLY from global per fragment --
// no ldsA at all. LDS carries only the B (feature) tile, double-buffered,
// one raw s_barrier + lgkmcnt(0) per K-step (no vmcnt drain in the loop).
__global__ __launch_bounds__(256, 3) void conv1_kernel(
    const unsigned short* __restrict__ w1b,   // [512][2048] bf16
    const float* __restrict__ feat,           // [4][2048][4096] f32
    unsigned short* __restrict__ zt)          // [4*4096][512] bf16
{
  __shared__ unsigned short ldsB[2][64 * 64];    // 2 x 8KB, swizzled [p][c]
  __shared__ unsigned short ldsT[64 * 256];      // 32KB epilogue transpose
  int t = threadIdx.x;
  int l = t & 63, wid = t >> 6;

  int bid = blockIdx.x;
  int lid = (bid & 7) * 64 + (bid >> 3);   // XCD-contiguous logical id
  int ohalf = lid & 1;                     // o-half pairs co-resident on one XCD
  int pbid = lid >> 1;                     // 0..255
  int bb = pbid >> 6;
  int p0 = (pbid & 63) << 6;

  // A fragment base: wave wid owns o-rows [oBase, oBase+64)
  int oBase = ohalf * 256 + wid * 64;
  const unsigned short* aFrag = w1b + ((size_t)(oBase + (l & 15))) * 2048 + (l >> 4) * 8;

  // B staging: thread loads rows c0..c0+3 (f32x4 along p at p4), coalesced
  int c0 = (t >> 4) << 2;
  int p4 = (t & 15) << 2;
  const float* fBase = feat + ((size_t)(bb * 2048 + c0)) * 4096 + p0 + p4;

  f32x4 acc[4][4];
  f32x4 z4 = {0.f, 0.f, 0.f, 0.f};
  #pragma unroll
  for (int m = 0; m < 4; ++m)
    #pragma unroll
    for (int n = 0; n < 4; ++n) acc[m][n] = z4;

  f32x4 rb[4];

#define LOAD_B(dst, kt) do {                                               \
    const float* fp_ = fBase + (size_t)(kt) * 4096;                        \
    dst[0] = *(const f32x4*)(fp_);                                         \
    dst[1] = *(const f32x4*)(fp_ + 4096);                                  \
    dst[2] = *(const f32x4*)(fp_ + 8192);                                  \
    dst[3] = *(const f32x4*)(fp_ + 12288);                                 \
  } while (0)

#define WRITE_B(buf, src) do {                                             \
    _Pragma("unroll")                                                      \
    for (int j = 0; j < 4; ++j){                                           \
      int p_ = p4 + j;                                                     \
      int f_ = (p_ ^ (p_ >> 3)) & 7;                                       \
      u32 lo_ = ((u32)f32_to_bf16(src[0][j])) | (((u32)f32_to_bf16(src[1][j])) << 16); \
      u32 hi_ = ((u32)f32_to_bf16(src[2][j])) | (((u32)f32_to_bf16(src[3][j])) << 16); \
      u64 v_ = ((u64)hi_ << 32) | lo_;                                     \
      *(u64*)((char*)ldsB[buf] + p_ * 128 + ((c0 * 2) ^ (f_ << 4))) = v_;  \
    }                                                                      \
  } while (0)

#define MFMA_STEP(buf, kt) do {                                            \
    u16x8 afr[2][4];                                                       \
    _Pragma("unroll")                                                      \
    for (int ks = 0; ks < 2; ++ks)                                         \
      _Pragma("unroll")                                                    \
      for (int m = 0; m < 4; ++m)                                          \
        afr[ks][m] = *(const u16x8*)(aFrag + (size_t)m * (16 * 2048) + (kt) + ks * 32); \
    __builtin_amdgcn_s_setprio(1);                                         \
    _Pragma("unroll")                                                      \
    for (int ks = 0; ks < 2; ++ks){                                        \
      bf16x8 bf_[4];                                                       \
      int cbyte_ = ks * 64 + (l >> 4) * 16;                                \
      _Pragma("unroll")                                                    \
      for (int n = 0; n < 4; ++n){                                         \
        int p_ = n * 16 + (l & 15);                                        \
        int f_ = (p_ ^ (p_ >> 3)) & 7;                                     \
        bf_[n] = *(const bf16x8*)((const char*)ldsB[buf] + p_ * 128 + (cbyte_ ^ (f_ << 4))); \
      }                                                                    \
      _Pragma("unroll")                                                    \
      for (int m = 0; m < 4; ++m)                                          \
        _Pragma("unroll")                                                  \
        for (int n = 0; n < 4; ++n)                                        \
          acc[m][n] = __builtin_amdgcn_mfma_f32_16x16x32_bf16(                \
              *(const bf16x8*)&afr[ks][m], bf_[n], acc[m][n], 0, 0, 0);    \
    }                                                                      \
    __builtin_amdgcn_s_setprio(0);                                         \
  } while (0)

  // prologue: tile0 -> ldsB[0]; tile1 -> rb
  LOAD_B(rb, 0);
  WRITE_B(0, rb);                 // compiler waits rb
  LOAD_B(rb, 64);
  asm volatile("s_waitcnt lgkmcnt(0)" ::: "memory");
  __builtin_amdgcn_s_barrier();
  __builtin_amdgcn_sched_barrier(0);

  // main loop: 31 staged steps + epilogue step
  for (int kt2 = 0; kt2 < 31; ++kt2){
    int cur = kt2 & 1, nxt = cur ^ 1;
    MFMA_STEP(cur, kt2 << 6);
    WRITE_B(nxt, rb);             // stage tile kt2+1 (waits its loads)
    if (kt2 < 30) LOAD_B(rb, (kt2 + 2) << 6);   // prefetch tile kt2+2
    asm volatile("s_waitcnt lgkmcnt(0)" ::: "memory");
    __builtin_amdgcn_s_barrier();
    __builtin_amdgcn_sched_barrier(0);
  }
  MFMA_STEP(1, 31 << 6);          // tile 31 lives in buf1
  __syncthreads();                // before reusing LDS for transpose

  // epilogue: stage 256o x 64p tile transposed into ldsT as [64p][256o*2B]
  #pragma unroll
  for (int m = 0; m < 4; ++m){
    int o0 = wid * 64 + m * 16 + (l >> 4) * 4;
    #pragma unroll
    for (int n = 0; n < 4; ++n){
      int p = n * 16 + (l & 15);
      u32 lo = ((u32)f32_to_bf16(acc[m][n][0])) | (((u32)f32_to_bf16(acc[m][n][1])) << 16);
      u32 hi = ((u32)f32_to_bf16(acc[m][n][2])) | (((u32)f32_to_bf16(acc[m][n][3])) << 16);
      u64 v = ((u64)hi << 32) | lo;
      *(u64*)((char*)ldsT + p * 512 + ((o0 * 2) ^ ((p & 7) << 4))) = v;
    }
  }
  __syncthreads();
  {
    int p = t >> 2, a = t & 3;
    size_t rowb = ((size_t)(bb * 4096 + p0 + p)) * 1024 + (size_t)ohalf * 512;
    int swz = (p & 7) << 4;
    #pragma unroll
    for (int j = 0; j < 8; ++j){
      int y = (a * 128 + j * 16) ^ swz;
      f32x4 v = *(const f32x4*)((char*)ldsT + p * 512 + y);
      *(f32x4*)((char*)zt + rowb + a * 128 + j * 16) = v;
    }
  }
#undef LOAD_B
#undef WRITE_B
#undef MFMA_STEP
}

// ---------- K2: ROI gather on Zt (512 ch) + BN1 + ReLU -> h1 bf16 [6272][512] ----------
__global__ __launch_bounds__(256) void roi_gather_kernel(
    const unsigned short* __restrict__ zt, const float* __restrict__ boxes,
    const float* __restrict__ sc1, const float* __restrict__ sh1,
    unsigned short* __restrict__ h1)
{
  int ky = blockIdx.x, roi = blockIdx.y;
  __shared__ int   sIdx[16][8];
  __shared__ float sW[16][8];
  int t = threadIdx.x;

  int   b   = (int)boxes[roi * 5 + 0];
  float bx1 = boxes[roi * 5 + 1], by1 = boxes[roi * 5 + 2];
  float bx2 = boxes[roi * 5 + 3], by2 = boxes[roi * 5 + 4];
  float rw = fmaxf(bx2 - bx1, 1.f), rh = fmaxf(by2 - by1, 1.f);
  float bw = rw * (1.f / 7.f), bh = rh * (1.f / 7.f);

  if (t < 28){
    int kx = t >> 2, s = t & 3;
    int sy = s >> 1, sx = s & 1;
    float yy = by1 + ((float)ky + ((float)sy + 0.5f) * 0.5f) * bh;
    float xx = bx1 + ((float)kx + ((float)sx + 0.5f) * 0.5f) * bw;
    bool vy = (yy >= -1.f) && (yy <= 64.f);
    bool vx = (xx >= -1.f) && (xx <= 64.f);
    float yc = fminf(fmaxf(yy, 0.f), 63.f);
    float xc = fminf(fmaxf(xx, 0.f), 63.f);
    int iy0 = (int)yc, ix0 = (int)xc;
    int iy1 = min(iy0 + 1, 63), ix1 = min(ix0 + 1, 63);
    float fy = yc - (float)iy0, fx = xc - (float)ix0;
    float v = (vy && vx) ? 0.25f : 0.f;
    float wy0 = 1.f - fy, wx0 = 1.f - fx;
    sIdx[s * 4 + 0][kx] = iy0 * 64 + ix0;  sW[s * 4 + 0][kx] = wy0 * wx0 * v;
    sIdx[s * 4 + 1][kx] = iy0 * 64 + ix1;  sW[s * 4 + 1][kx] = wy0 * fx  * v;
    sIdx[s * 4 + 2][kx] = iy1 * 64 + ix0;  sW[s * 4 + 2][kx] = fy  * wx0 * v;
    sIdx[s * 4 + 3][kx] = iy1 * 64 + ix1;  sW[s * 4 + 3][kx] = fy  * fx  * v;
  }
  __syncthreads();

  int w = t >> 6, l = t & 63;
  f32x4 s0 = *(const f32x4*)(sc1 + l * 8);
  f32x4 s1 = *(const f32x4*)(sc1 + l * 8 + 4);
  f32x4 h0 = *(const f32x4*)(sh1 + l * 8);
  f32x4 hh = *(const f32x4*)(sh1 + l * 8 + 4);
  const unsigned short* zb = zt + ((size_t)b * 4096) * 512 + l * 8;

  for (int kx = w; kx < 7; kx += 4){
    float a[8];
    #pragma unroll
    for (int j = 0; j < 8; ++j) a[j] = 0.f;
    #pragma unroll
    for (int i = 0; i < 16; ++i){
      int idx = sIdx[i][kx];
      float wt = sW[i][kx];
      u16x8 v = *(const u16x8*)(zb + (size_t)idx * 512);
      #pragma unroll
      for (int j = 0; j < 8; ++j) a[j] += wt * bf16_to_f32(v[j]);
    }
    u16x8 o;
    #pragma unroll
    for (int j = 0; j < 4; ++j){
      float v0 = fmaxf(a[j] * s0[j] + h0[j], 0.f);
      float v1 = fmaxf(a[j + 4] * s1[j] + hh[j], 0.f);
      o[j] = f32_to_bf16(v0);
      o[j + 4] = f32_to_bf16(v1);
    }
    *(u16x8*)(h1 + ((size_t)(roi * 49 + ky * 7 + kx)) * 512 + l * 8) = o;
  }
}

// ---------- K3: bf16 GEMM, B-transposed input, fused scale/shift + ReLU ----------
template<int BM, int BN>
__global__ __launch_bounds__(256) void gemm_bt_relu(
    const unsigned short* __restrict__ A, const unsigned short* __restrict__ Bt,
    const float* __restrict__ scale, const float* __restrict__ shift,
    unsigned short* __restrict__ C, int M, int N, int K)
{
  constexpr int BK = 64;
  constexpr int FM = BM / 32;
  constexpr int FN = BN / 32;
  __shared__ unsigned short lds_a[BM * BK];
  __shared__ unsigned short lds_b[BN * BK];
  int t = threadIdx.x;
  int l = t & 63, wid = t >> 6;
  int wr = wid >> 1, wc = wid & 1;
  int m0 = blockIdx.y * BM, n0 = blockIdx.x * BN;

  f32x4 acc[FM][FN];
  f32x4 z = {0.f, 0.f, 0.f, 0.f};
  #pragma unroll
  for (int m = 0; m < FM; ++m)
    #pragma unroll
    for (int n = 0; n < FN; ++n) acc[m][n] = z;

  const unsigned short* Ab = A  + (size_t)m0 * K;
  const unsigned short* Bb = Bt + (size_t)n0 * K;

  for (int kt = 0; kt < K; kt += BK){
    #pragma unroll
    for (int r = 0; r < BM / 32; ++r){
      int row = r * 32 + (t >> 3);
      GLOAD_LDS16(Ab + (size_t)row * K + kt + (t & 7) * 8,
                  lds_a + row * BK + (t & 7) * 8);
    }
    #pragma unroll
    for (int r = 0; r < BN / 32; ++r){
      int row = r * 32 + (t >> 3);
      GLOAD_LDS16(Bb + (size_t)row * K + kt + (t & 7) * 8,
                  lds_b + row * BK + (t & 7) * 8);
    }
    __syncthreads();
    #pragma unroll
    for (int ks = 0; ks < 2; ++ks){
      bf16x8 af[FM], bfr[FN];
      #pragma unroll
      for (int m = 0; m < FM; ++m)
        af[m] = *reinterpret_cast<const bf16x8*>(
            lds_a + (wr * (BM / 2) + m * 16 + (l & 15)) * BK + ks * 32 + (l >> 4) * 8);
      #pragma unroll
      for (int n = 0; n < FN; ++n)
        bfr[n] = *reinterpret_cast<const bf16x8*>(
            lds_b + (wc * (BN / 2) + n * 16 + (l & 15)) * BK + ks * 32 + (l >> 4) * 8);
      #pragma unroll
      for (int m = 0; m < FM; ++m)
        #pragma unroll
        for (int n = 0; n < FN; ++n)
          acc[m][n] = __builtin_amdgcn_mfma_f32_16x16x32_bf16(af[m], bfr[n], acc[m][n], 0, 0, 0);
    }
    __syncthreads();
  }

  #pragma unroll
  for (int m = 0; m < FM; ++m){
    int gr = m0 + wr * (BM / 2) + m * 16 + (l >> 4) * 4;
    #pragma unroll
    for (int n = 0; n < FN; ++n){
      int gc = n0 + wc * (BN / 2) + n * 16 + (l & 15);
      float sc = scale[gc], sh = shift[gc];
      #pragma unroll
      for (int r = 0; r < 4; ++r){
        float v = acc[m][n][r] * sc + sh;
        v = fmaxf(v, 0.f);
        C[(size_t)(gr + r) * N + gc] = f32_to_bf16(v);
      }
    }
  }
}

// ---------- K4: mean over 49 bins -> out f32 [128][256] ----------
__global__ __launch_bounds__(256) void reduce_kernel(
    const unsigned short* __restrict__ h2, float* __restrict__ out)
{
  int n = blockIdx.x, o = threadIdx.x;
  const unsigned short* p = h2 + (size_t)n * 49 * 256 + o;
  float s = 0.f;
  for (int j = 0; j < 49; ++j) s += bf16_to_f32(p[j * 256]);
  out[n * 256 + o] = s * (1.f / 49.f);
}

// ---------- launch ----------
extern "C" void kernel_launch(void* const* d_in, const int* in_sizes, int n_in,
                              void* d_out, int out_size, void* d_ws, size_t ws_size,
                              hipStream_t stream)
{
  const float* feat  = (const float*)d_in[0];
  const float* boxes = (const float*)d_in[1];
  const float* w1  = (const float*)d_in[2];
  const float* b1  = (const float*)d_in[3];
  const float* g1  = (const float*)d_in[4];
  const float* be1 = (const float*)d_in[5];
  const float* m1  = (const float*)d_in[6];
  const float* v1  = (const float*)d_in[7];
  const float* w2  = (const float*)d_in[8];
  const float* b2  = (const float*)d_in[9];
  const float* g2  = (const float*)d_in[10];
  const float* be2 = (const float*)d_in[11];
  const float* m2  = (const float*)d_in[12];
  const float* v2  = (const float*)d_in[13];
  float* out = (float*)d_out;

  char* ws = (char*)d_ws;
  unsigned short* w1b = (unsigned short*)(ws);                         // 2 MB
  unsigned short* w2b = (unsigned short*)(ws + (2u << 20));            // 256 KB
  float* sc1 = (float*)(ws + (2u << 20) + (256u << 10));
  float* sh1 = sc1 + 512;
  float* sc2 = sh1 + 512;
  float* sh2 = sc2 + 256;
  unsigned short* zt = (unsigned short*)(ws + (4u  << 20));            // 16.8 MB
  unsigned short* h1 = (unsigned short*)(ws + (24u << 20));            // 6.4 MB
  unsigned short* h2 = (unsigned short*)(ws + (32u << 20));            // 3.2 MB

  hipLaunchKernelGGL(prep_kernel, dim3(256), dim3(256), 0, stream,
                     w1, w2, b1, g1, be1, m1, v1, b2, g2, be2, m2, v2,
                     w1b, w2b, sc1, sh1, sc2, sh2);
  hipLaunchKernelGGL(conv1_kernel, dim3(512), dim3(256), 0, stream,
                     w1b, feat, zt);
  hipLaunchKernelGGL(roi_gather_kernel, dim3(7, 128), dim3(256), 0, stream,
                     zt, boxes, sc1, sh1, h1);
  hipLaunchKernelGGL(HIP_KERNEL_NAME(gemm_bt_relu<128, 64>),
                     dim3(256 / 64, 6272 / 128), dim3(256), 0, stream,
                     h1, w2b, sc2, sh2, h2, 6272, 256, 512);
  hipLaunchKernelGGL(reduce_kernel, dim3(128), dim3(256), 0, stream, h2, out);
}

// Round 6
// 99.700 us; speedup vs baseline: 1.1040x; 1.1040x over previous
//
#include <hip/hip_runtime.h>

// ---------- helpers ----------
typedef __bf16 bf16x8 __attribute__((ext_vector_type(8)));
typedef float  f32x4  __attribute__((ext_vector_type(4)));
typedef unsigned short u16x8 __attribute__((ext_vector_type(8)));
typedef unsigned int u32;
typedef unsigned long long u64;

static __device__ __forceinline__ unsigned short f32_to_bf16(float f){
  unsigned u = __float_as_uint(f);
  u += 0x7fffu + ((u >> 16) & 1u);          // round-to-nearest-even
  return (unsigned short)(u >> 16);
}
static __device__ __forceinline__ float bf16_to_f32(unsigned short h){
  return __uint_as_float(((unsigned)h) << 16);
}

#define GLOAD_LDS16(g, l)                                                        \
  __builtin_amdgcn_global_load_lds((const __attribute__((address_space(1))) void*)(g), \
                                   (__attribute__((address_space(3))) void*)(l), 16, 0, 0)

// ---------- K0: weight conversion + BN folding ----------
__global__ __launch_bounds__(256) void prep_kernel(
    const float* __restrict__ w1, const float* __restrict__ w2,
    const float* __restrict__ b1, const float* __restrict__ g1, const float* __restrict__ be1,
    const float* __restrict__ m1, const float* __restrict__ v1,
    const float* __restrict__ b2, const float* __restrict__ g2, const float* __restrict__ be2,
    const float* __restrict__ m2, const float* __restrict__ v2,
    unsigned short* __restrict__ w1b, unsigned short* __restrict__ w2b,
    float* __restrict__ sc1, float* __restrict__ sh1,
    float* __restrict__ sc2, float* __restrict__ sh2)
{
  int i = blockIdx.x * 256 + threadIdx.x;
  int stride = gridDim.x * 256;
  for (int k = i; k < 512 * 2048; k += stride) w1b[k] = f32_to_bf16(w1[k]);
  for (int k = i; k < 256 * 512;  k += stride) w2b[k] = f32_to_bf16(w2[k]);
  if (i < 512){
    float s = g1[i] * rsqrtf(v1[i] + 1e-5f);
    sc1[i] = s;
    sh1[i] = (b1[i] - m1[i]) * s + be1[i];   // conv bias folded into BN shift
  } else if (i - 512 < 256){
    int o = i - 512;
    float s = g2[o] * rsqrtf(v2[o] + 1e-5f);
    sc2[o] = s;
    sh2[o] = (b2[o] - m2[o]) * s + be2[o];
  }
}

// ---------- K1: conv1 full map: Zt[b*4096+p][512] = (W1 . F)^T, bf16 ----------
// Tile 512o x 64p: one block computes ALL 512 out-channels for its 64 positions
// -> features read exactly once chip-wide. grid 256 = 1 block/CU, 8 waves.
// Counted-vmcnt single-barrier pipeline; A/B LDS double-buffered.
__global__ __launch_bounds__(512, 2) void conv1_kernel(
    const unsigned short* __restrict__ w1b,   // [512][2048] bf16
    const float* __restrict__ feat,           // [4][2048][4096] f32
    unsigned short* __restrict__ zt)          // [4*4096][512] bf16
{
  __shared__ unsigned short ldsA[2][512 * 64];   // 2 x 64KB, swizzled [o][c]
  __shared__ unsigned short ldsB[2][64 * 64];    // 2 x 8KB,  swizzled [p][c]
  int t = threadIdx.x;
  int l = t & 63, wid = t >> 6;

  int bid = blockIdx.x;
  int bb = bid >> 6;
  int p0 = (bid & 63) << 6;

  // A staging: 4096 slots of 16B; slot = i*512+t; o = i*64 + (t>>3); x = (t&7)*16B
  // stored content at [o][x] = element c = (x ^ ((o&7)<<4))>>1  (pre-swizzled source)
  int oA = t >> 3;
  int xA = (t & 7) << 4;
  const unsigned short* aBase = w1b + ((size_t)oA) * 2048 + ((xA ^ ((oA & 7) << 4)) >> 1);

  // B staging: thread loads c = c0, c0+1 (f32x4 along p at p4)
  int c0 = (t >> 4) << 1;          // 0..62
  int p4 = (t & 15) << 2;          // 0..60
  const float* fBase = feat + ((size_t)(bb * 2048 + c0)) * 4096 + p0 + p4;

  f32x4 acc[4][4];
  f32x4 z4 = {0.f, 0.f, 0.f, 0.f};
  #pragma unroll
  for (int m = 0; m < 4; ++m)
    #pragma unroll
    for (int n = 0; n < 4; ++n) acc[m][n] = z4;

  f32x4 rb[2];

#define STAGE_A(buf, kt) do {                                              \
    _Pragma("unroll")                                                      \
    for (int i = 0; i < 8; ++i)                                            \
      GLOAD_LDS16(aBase + (kt) + (size_t)i * (64 * 2048),                  \
                  (unsigned short*)ldsA[buf] + ((i * 512 + t) * 8));       \
  } while (0)

#define LOAD_B(dst, kt) do {                                               \
    const float* fp_ = fBase + (size_t)(kt) * 4096;                        \
    dst[0] = *(const f32x4*)(fp_);                                         \
    dst[1] = *(const f32x4*)(fp_ + 4096);                                  \
  } while (0)

#define WRITE_B(buf, src) do {                                             \
    _Pragma("unroll")                                                      \
    for (int jj = 0; jj < 4; ++jj){                                        \
      int p_ = p4 + jj;                                                    \
      int f_ = (p_ ^ (p_ >> 3)) & 7;                                       \
      u32 v_ = ((u32)f32_to_bf16(src[0][jj])) | (((u32)f32_to_bf16(src[1][jj])) << 16); \
      *(u32*)((char*)ldsB[buf] + p_ * 128 + ((c0 * 2) ^ (f_ << 4))) = v_;  \
    }                                                                      \
  } while (0)

#define MFMA_STEP(buf) do {                                                \
    bf16x8 af_[2][4], bf_[2][4];                                           \
    _Pragma("unroll")                                                      \
    for (int ks = 0; ks < 2; ++ks){                                        \
      int cbyte_ = ks * 64 + (l >> 4) * 16;                                \
      _Pragma("unroll")                                                    \
      for (int m = 0; m < 4; ++m){                                         \
        int o_ = wid * 64 + m * 16 + (l & 15);                             \
        af_[ks][m] = *(const bf16x8*)((const char*)ldsA[buf] + o_ * 128 + (cbyte_ ^ ((o_ & 7) << 4))); \
      }                                                                    \
      _Pragma("unroll")                                                    \
      for (int n = 0; n < 4; ++n){                                         \
        int p_ = n * 16 + (l & 15);                                        \
        int f_ = (p_ ^ (p_ >> 3)) & 7;                                     \
        bf_[ks][n] = *(const bf16x8*)((const char*)ldsB[buf] + p_ * 128 + (cbyte_ ^ (f_ << 4))); \
      }                                                                    \
    }                                                                      \
    __builtin_amdgcn_s_setprio(1);                                         \
    _Pragma("unroll")                                                      \
    for (int ks = 0; ks < 2; ++ks)                                         \
      _Pragma("unroll")                                                    \
      for (int m = 0; m < 4; ++m)                                          \
        _Pragma("unroll")                                                  \
        for (int n = 0; n < 4; ++n)                                        \
          acc[m][n] = __builtin_amdgcn_mfma_f32_16x16x32_bf16(af_[ks][m], bf_[ks][n], acc[m][n], 0, 0, 0); \
    __builtin_amdgcn_s_setprio(0);                                         \
  } while (0)

  // prologue: B(0)->regs, A(0)->ldsA[0]; publish buf0
  LOAD_B(rb, 0);
  STAGE_A(0, 0);
  __builtin_amdgcn_sched_barrier(0);
  asm volatile("s_waitcnt vmcnt(8)" ::: "memory");   // rb landed; A(0) in flight
  WRITE_B(0, rb);
  asm volatile("s_waitcnt lgkmcnt(0)" ::: "memory");
  __builtin_amdgcn_s_barrier();
  // invariant at loop top: outstanding vmem = [A(cur) x8]

  for (int s = 0; s < 32; ++s){
    int cur = s & 1, nxt = cur ^ 1;
    int ktn = (s + 1 < 32 ? s + 1 : 31) << 6;        // prefetch (clamped; tail redundant)
    LOAD_B(rb, ktn);                                  // queue: [A_cur 8, B 2]
    __builtin_amdgcn_sched_barrier(0);
    asm volatile("s_waitcnt vmcnt(2)" ::: "memory");  // A(cur) DMA complete
    __builtin_amdgcn_sched_barrier(0);
    STAGE_A(nxt, ktn);                                // queue: [B 2, A_nxt 8]
    __builtin_amdgcn_sched_barrier(0);
    MFMA_STEP(cur);
    asm volatile("s_waitcnt vmcnt(8)" ::: "memory");  // B landed; A_nxt stays in flight
    __builtin_amdgcn_sched_barrier(0);
    WRITE_B(nxt, rb);
    asm volatile("s_waitcnt lgkmcnt(0)" ::: "memory");
    __builtin_amdgcn_sched_barrier(0);
    __builtin_amdgcn_s_barrier();
  }
  __syncthreads();   // drain; ldsA reused below

  // epilogue: stage 512o x 64p transposed into ldsA as [64p][512o*2B rows]
  #pragma unroll
  for (int m = 0; m < 4; ++m){
    int o0 = wid * 64 + m * 16 + (l >> 4) * 4;
    #pragma unroll
    for (int n = 0; n < 4; ++n){
      int p = n * 16 + (l & 15);
      u32 lo = ((u32)f32_to_bf16(acc[m][n][0])) | (((u32)f32_to_bf16(acc[m][n][1])) << 16);
      u32 hi = ((u32)f32_to_bf16(acc[m][n][2])) | (((u32)f32_to_bf16(acc[m][n][3])) << 16);
      u64 v = ((u64)hi << 32) | lo;
      *(u64*)((char*)ldsA[0] + p * 1024 + ((o0 * 2) ^ ((p & 7) << 4))) = v;
    }
  }
  __syncthreads();
  {
    int p = t >> 3, a = t & 7;
    size_t rowb = ((size_t)(bb * 4096 + p0 + p)) * 1024;
    int swz = (p & 7) << 4;
    #pragma unroll
    for (int j = 0; j < 8; ++j){
      int y = (a * 16 + j * 128) ^ swz;
      f32x4 v = *(const f32x4*)((char*)ldsA[0] + p * 1024 + y);
      *(f32x4*)((char*)zt + rowb + a * 16 + j * 128) = v;
    }
  }
#undef STAGE_A
#undef LOAD_B
#undef WRITE_B
#undef MFMA_STEP
}

// ---------- K2: ROI gather on Zt (512 ch) + BN1 + ReLU -> h1 bf16 [6272][512] ----------
__global__ __launch_bounds__(256) void roi_gather_kernel(
    const unsigned short* __restrict__ zt, const float* __restrict__ boxes,
    const float* __restrict__ sc1, const float* __restrict__ sh1,
    unsigned short* __restrict__ h1)
{
  int ky = blockIdx.x, roi = blockIdx.y;
  __shared__ int   sIdx[16][8];
  __shared__ float sW[16][8];
  int t = threadIdx.x;

  int   b   = (int)boxes[roi * 5 + 0];
  float bx1 = boxes[roi * 5 + 1], by1 = boxes[roi * 5 + 2];
  float bx2 = boxes[roi * 5 + 3], by2 = boxes[roi * 5 + 4];
  float rw = fmaxf(bx2 - bx1, 1.f), rh = fmaxf(by2 - by1, 1.f);
  float bw = rw * (1.f / 7.f), bh = rh * (1.f / 7.f);

  if (t < 28){
    int kx = t >> 2, s = t & 3;
    int sy = s >> 1, sx = s & 1;
    float yy = by1 + ((float)ky + ((float)sy + 0.5f) * 0.5f) * bh;
    float xx = bx1 + ((float)kx + ((float)sx + 0.5f) * 0.5f) * bw;
    bool vy = (yy >= -1.f) && (yy <= 64.f);
    bool vx = (xx >= -1.f) && (xx <= 64.f);
    float yc = fminf(fmaxf(yy, 0.f), 63.f);
    float xc = fminf(fmaxf(xx, 0.f), 63.f);
    int iy0 = (int)yc, ix0 = (int)xc;
    int iy1 = min(iy0 + 1, 63), ix1 = min(ix0 + 1, 63);
    float fy = yc - (float)iy0, fx = xc - (float)ix0;
    float v = (vy && vx) ? 0.25f : 0.f;
    float wy0 = 1.f - fy, wx0 = 1.f - fx;
    sIdx[s * 4 + 0][kx] = iy0 * 64 + ix0;  sW[s * 4 + 0][kx] = wy0 * wx0 * v;
    sIdx[s * 4 + 1][kx] = iy0 * 64 + ix1;  sW[s * 4 + 1][kx] = wy0 * fx  * v;
    sIdx[s * 4 + 2][kx] = iy1 * 64 + ix0;  sW[s * 4 + 2][kx] = fy  * wx0 * v;
    sIdx[s * 4 + 3][kx] = iy1 * 64 + ix1;  sW[s * 4 + 3][kx] = fy  * fx  * v;
  }
  __syncthreads();

  int w = t >> 6, l = t & 63;
  f32x4 s0 = *(const f32x4*)(sc1 + l * 8);
  f32x4 s1 = *(const f32x4*)(sc1 + l * 8 + 4);
  f32x4 h0 = *(const f32x4*)(sh1 + l * 8);
  f32x4 hh = *(const f32x4*)(sh1 + l * 8 + 4);
  const unsigned short* zb = zt + ((size_t)b * 4096) * 512 + l * 8;

  for (int kx = w; kx < 7; kx += 4){
    float a[8];
    #pragma unroll
    for (int j = 0; j < 8; ++j) a[j] = 0.f;
    #pragma unroll
    for (int i = 0; i < 16; ++i){
      int idx = sIdx[i][kx];
      float wt = sW[i][kx];
      u16x8 v = *(const u16x8*)(zb + (size_t)idx * 512);
      #pragma unroll
      for (int j = 0; j < 8; ++j) a[j] += wt * bf16_to_f32(v[j]);
    }
    u16x8 o;
    #pragma unroll
    for (int j = 0; j < 4; ++j){
      float v0 = fmaxf(a[j] * s0[j] + h0[j], 0.f);
      float v1 = fmaxf(a[j + 4] * s1[j] + hh[j], 0.f);
      o[j] = f32_to_bf16(v0);
      o[j + 4] = f32_to_bf16(v1);
    }
    *(u16x8*)(h1 + ((size_t)(roi * 49 + ky * 7 + kx)) * 512 + l * 8) = o;
  }
}

// ---------- K3: bf16 GEMM, B-transposed input, fused scale/shift + ReLU ----------
template<int BM, int BN>
__global__ __launch_bounds__(256) void gemm_bt_relu(
    const unsigned short* __restrict__ A, const unsigned short* __restrict__ Bt,
    const float* __restrict__ scale, const float* __restrict__ shift,
    unsigned short* __restrict__ C, int M, int N, int K)
{
  constexpr int BK = 64;
  constexpr int FM = BM / 32;
  constexpr int FN = BN / 32;
  __shared__ unsigned short lds_a[BM * BK];
  __shared__ unsigned short lds_b[BN * BK];
  int t = threadIdx.x;
  int l = t & 63, wid = t >> 6;
  int wr = wid >> 1, wc = wid & 1;
  int m0 = blockIdx.y * BM, n0 = blockIdx.x * BN;

  f32x4 acc[FM][FN];
  f32x4 z = {0.f, 0.f, 0.f, 0.f};
  #pragma unroll
  for (int m = 0; m < FM; ++m)
    #pragma unroll
    for (int n = 0; n < FN; ++n) acc[m][n] = z;

  const unsigned short* Ab = A  + (size_t)m0 * K;
  const unsigned short* Bb = Bt + (size_t)n0 * K;

  for (int kt = 0; kt < K; kt += BK){
    #pragma unroll
    for (int r = 0; r < BM / 32; ++r){
      int row = r * 32 + (t >> 3);
      GLOAD_LDS16(Ab + (size_t)row * K + kt + (t & 7) * 8,
                  lds_a + row * BK + (t & 7) * 8);
    }
    #pragma unroll
    for (int r = 0; r < BN / 32; ++r){
      int row = r * 32 + (t >> 3);
      GLOAD_LDS16(Bb + (size_t)row * K + kt + (t & 7) * 8,
                  lds_b + row * BK + (t & 7) * 8);
    }
    __syncthreads();
    #pragma unroll
    for (int ks = 0; ks < 2; ++ks){
      bf16x8 af[FM], bfr[FN];
      #pragma unroll
      for (int m = 0; m < FM; ++m)
        af[m] = *reinterpret_cast<const bf16x8*>(
            lds_a + (wr * (BM / 2) + m * 16 + (l & 15)) * BK + ks * 32 + (l >> 4) * 8);
      #pragma unroll
      for (int n = 0; n < FN; ++n)
        bfr[n] = *reinterpret_cast<const bf16x8*>(
            lds_b + (wc * (BN / 2) + n * 16 + (l & 15)) * BK + ks * 32 + (l >> 4) * 8);
      #pragma unroll
      for (int m = 0; m < FM; ++m)
        #pragma unroll
        for (int n = 0; n < FN; ++n)
          acc[m][n] = __builtin_amdgcn_mfma_f32_16x16x32_bf16(af[m], bfr[n], acc[m][n], 0, 0, 0);
    }
    __syncthreads();
  }

  #pragma unroll
  for (int m = 0; m < FM; ++m){
    int gr = m0 + wr * (BM / 2) + m * 16 + (l >> 4) * 4;
    #pragma unroll
    for (int n = 0; n < FN; ++n){
      int gc = n0 + wc * (BN / 2) + n * 16 + (l & 15);
      float sc = scale[gc], sh = shift[gc];
      #pragma unroll
      for (int r = 0; r < 4; ++r){
        float v = acc[m][n][r] * sc + sh;
        v = fmaxf(v, 0.f);
        C[(size_t)(gr + r) * N + gc] = f32_to_bf16(v);
      }
    }
  }
}

// ---------- K4: mean over 49 bins -> out f32 [128][256] ----------
__global__ __launch_bounds__(256) void reduce_kernel(
    const unsigned short* __restrict__ h2, float* __restrict__ out)
{
  int n = blockIdx.x, o = threadIdx.x;
  const unsigned short* p = h2 + (size_t)n * 49 * 256 + o;
  float s = 0.f;
  for (int j = 0; j < 49; ++j) s += bf16_to_f32(p[j * 256]);
  out[n * 256 + o] = s * (1.f / 49.f);
}

// ---------- launch ----------
extern "C" void kernel_launch(void* const* d_in, const int* in_sizes, int n_in,
                              void* d_out, int out_size, void* d_ws, size_t ws_size,
                              hipStream_t stream)
{
  const float* feat  = (const float*)d_in[0];
  const float* boxes = (const float*)d_in[1];
  const float* w1  = (const float*)d_in[2];
  const float* b1  = (const float*)d_in[3];
  const float* g1  = (const float*)d_in[4];
  const float* be1 = (const float*)d_in[5];
  const float* m1  = (const float*)d_in[6];
  const float* v1  = (const float*)d_in[7];
  const float* w2  = (const float*)d_in[8];
  const float* b2  = (const float*)d_in[9];
  const float* g2  = (const float*)d_in[10];
  const float* be2 = (const float*)d_in[11];
  const float* m2  = (const float*)d_in[12];
  const float* v2  = (const float*)d_in[13];
  float* out = (float*)d_out;

  char* ws = (char*)d_ws;
  unsigned short* w1b = (unsigned short*)(ws);                         // 2 MB
  unsigned short* w2b = (unsigned short*)(ws + (2u << 20));            // 256 KB
  float* sc1 = (float*)(ws + (2u << 20) + (256u << 10));
  float* sh1 = sc1 + 512;
  float* sc2 = sh1 + 512;
  float* sh2 = sc2 + 256;
  unsigned short* zt = (unsigned short*)(ws + (4u  << 20));            // 16.8 MB
  unsigned short* h1 = (unsigned short*)(ws + (24u << 20));            // 6.4 MB
  unsigned short* h2 = (unsigned short*)(ws + (32u << 20));            // 3.2 MB

  hipLaunchKernelGGL(prep_kernel, dim3(256), dim3(256), 0, stream,
                     w1, w2, b1, g1, be1, m1, v1, b2, g2, be2, m2, v2,
                     w1b, w2b, sc1, sh1, sc2, sh2);
  hipLaunchKernelGGL(conv1_kernel, dim3(256), dim3(512), 0, stream,
                     w1b, feat, zt);
  hipLaunchKernelGGL(roi_gather_kernel, dim3(7, 128), dim3(256), 0, stream,
                     zt, boxes, sc1, sh1, h1);
  hipLaunchKernelGGL(HIP_KERNEL_NAME(gemm_bt_relu<128, 64>),
                     dim3(256 / 64, 6272 / 128), dim3(256), 0, stream,
                     h1, w2b, sc2, sh2, h2, 6272, 256, 512);
  hipLaunchKernelGGL(reduce_kernel, dim3(128), dim3(256), 0, stream, h2, out);
}